// Round 13
// baseline (230.828 us; speedup 1.0000x reference)
//
#include <hip/hip_runtime.h>

// YOLOv1 loss, DMA-staged single kernel with fused last-block reduction.
// R9/R11/R12 (5-stream burst / 5-stream continuous / 10-stream burst) all land
// 39-43us = ~87% of the per-CU streaming ubench rate -> the DMA stream is at
// its practical ceiling. Remaining overhead: 2nd kernel launch + partial-reduce.
// Here: completion counter (threadfence + device-scope atomicAdd); the last
// block reduces 3136 partials in fixed order (deterministic) and writes d_out.

constexpr int SS  = 14;
constexpr int TPB = 64;                  // one wave
constexpr int CPT = 64;                  // cells per tile
constexpr int TFL = CPT * 30;            // floats per tensor per tile = 1920

typedef unsigned int u32;
typedef __attribute__((address_space(3))) u32 lds_u32;
typedef __attribute__((address_space(1))) const u32 glb_u32;

__device__ __forceinline__ void box_loss(
    float p0, float p1, float p2, float p3, float p4,
    float p5, float p6, float p7, float p8, float p9,
    float t0, float t1, float t2, float t3, float t4,
    float offx, float offy,
    float& s0, float& s1, float& s2, float& s3, float& m_out)
{
    float m  = (t4 == 1.0f) ? 1.0f : 0.0f;
    float nm = (t4 == 0.0f) ? 1.0f : 0.0f;
    m_out = m;

    const float S = 14.0f;
    float tcx = t0 / S + offx / S;
    float tcy = t1 / S + offy / S;
    float thw = 0.5f * t2, thh = 0.5f * t3;
    float tx0 = tcx - thw, ty0 = tcy - thh;
    float tx1 = tcx + thw, ty1 = tcy + thh;
    float area_t = t2 * t3;

    float iou0, iou1;
    {
        float cx = p0 / S + offx / S, cy = p1 / S + offy / S;
        float hw = 0.5f * p2, hh = 0.5f * p3;
        float x0 = cx - hw, y0 = cy - hh, x1 = cx + hw, y1 = cy + hh;
        float wx = fmaxf(fminf(tx1, x1) - fmaxf(tx0, x0), 0.f);
        float wy = fmaxf(fminf(ty1, y1) - fmaxf(ty0, y0), 0.f);
        float inter = wx * wy;
        iou0 = inter / (area_t + p2 * p3 - inter);
    }
    {
        float cx = p5 / S + offx / S, cy = p6 / S + offy / S;
        float hw = 0.5f * p7, hh = 0.5f * p8;
        float x0 = cx - hw, y0 = cy - hh, x1 = cx + hw, y1 = cy + hh;
        float wx = fmaxf(fminf(tx1, x1) - fmaxf(tx0, x0), 0.f);
        float wy = fmaxf(fminf(ty1, y1) - fmaxf(ty0, y0), 0.f);
        float inter = wx * wy;
        iou1 = inter / (area_t + p7 * p8 - inter);
    }

    int k = (iou1 > iou0) ? 1 : 0;     // jnp.argmax first-max tie-break
    float b0 = k ? p5 : p0, b1 = k ? p6 : p1;
    float b2 = k ? p7 : p2, b3 = k ? p8 : p3, b4 = k ? p9 : p4;
    float biou = k ? iou1 : iou0;

    float d0 = t0 - b0, d1 = t1 - b1;
    s0 += m * (d0 * d0 + d1 * d1);

    float e0 = sqrtf(t2) - sqrtf(b2);
    float e1 = sqrtf(t3) - sqrtf(b3);
    s1 += m * (e0 * e0 + e1 * e1);

    float dc = biou - b4;
    s2 += m * dc * dc;

    float conf_other = k ? p4 : p9;
    s3 += nm * (p4 * p4 + p9 * p9) + m * conf_other * conf_other;
}

__global__ __launch_bounds__(TPB) void yolo_fused(
    const float* __restrict__ pred,
    const float* __restrict__ targ,
    float4* __restrict__ partA,   // per-block {xy, wh, Cobj, Cnoobj}
    float*  __restrict__ partB,   // per-block cls
    u32*    __restrict__ counter, // completion counter (memset 0 each launch)
    float*  __restrict__ out,
    int ntiles, int nblocks, float invN)
{
    __shared__ __align__(16) float Lraw[2 * TFL];   // 15360B: pred | targ
    const int lane = threadIdx.x;

    float s0 = 0.f, s1 = 0.f, s2 = 0.f, s3 = 0.f, s4 = 0.f;
    const size_t tb0 = (size_t)blockIdx.x * ntiles;

#pragma unroll 1
    for (int t = 0; t < ntiles; ++t) {
        // previous tile's ds_reads must drain before DMA overwrites LDS
        if (t) { asm volatile("s_waitcnt lgkmcnt(0)" ::: "memory");
                 __builtin_amdgcn_sched_barrier(0); }

        const float* ps = pred + (tb0 + t) * TFL;
        const float* ts = targ + (tb0 + t) * TFL;
        // burst stage: 2 tensors x (7 full-wave + 1 half-wave) 16B DMA loads
#pragma unroll
        for (int i = 0; i < 7; ++i) {
            __builtin_amdgcn_global_load_lds((glb_u32*)(ps + i * 256 + lane * 4),
                                             (lds_u32*)(Lraw + i * 256), 16, 0, 0);
            __builtin_amdgcn_global_load_lds((glb_u32*)(ts + i * 256 + lane * 4),
                                             (lds_u32*)(Lraw + TFL + i * 256), 16, 0, 0);
        }
        if (lane < 32) {   // last 512B of each tensor
            __builtin_amdgcn_global_load_lds((glb_u32*)(ps + 1792 + lane * 4),
                                             (lds_u32*)(Lraw + 1792), 16, 0, 0);
            __builtin_amdgcn_global_load_lds((glb_u32*)(ts + 1792 + lane * 4),
                                             (lds_u32*)(Lraw + TFL + 1792), 16, 0, 0);
        }
        asm volatile("s_waitcnt vmcnt(0)" ::: "memory");
        __builtin_amdgcn_sched_barrier(0);
        // single wave per block: no s_barrier needed

        // ---- compute: one CELL per lane (120B = 15 float2, 8B-aligned) ----
        const float2* Pc = reinterpret_cast<const float2*>(Lraw) + lane * 15;
        const float2* Tc = reinterpret_cast<const float2*>(Lraw + TFL) + lane * 15;
        float2 a0 = Pc[0],  a1 = Pc[1],  a2 = Pc[2],  a3 = Pc[3],  a4 = Pc[4];
        float2 a5 = Pc[5],  a6 = Pc[6],  a7 = Pc[7],  a8 = Pc[8],  a9 = Pc[9];
        float2 a10 = Pc[10], a11 = Pc[11], a12 = Pc[12], a13 = Pc[13], a14 = Pc[14];
        float2 b0 = Tc[0],  b1 = Tc[1],  b2 = Tc[2];
        float2 b5 = Tc[5],  b6 = Tc[6],  b7 = Tc[7],  b8 = Tc[8],  b9 = Tc[9];
        float2 b10 = Tc[10], b11 = Tc[11], b12 = Tc[12], b13 = Tc[13], b14 = Tc[14];

        unsigned gcell = (unsigned)(tb0 + t) * CPT + (unsigned)lane;
        unsigned ij = gcell % 196u;
        float offx = (float)(ij % 14u);   // off = (j, i): x = column
        float offy = (float)(ij / 14u);

        float m;
        box_loss(a0.x, a0.y, a1.x, a1.y, a2.x, a2.y, a3.x, a3.y, a4.x, a4.y,
                 b0.x, b0.y, b1.x, b1.y, b2.x, offx, offy, s0, s1, s2, s3, m);

        // class: elems 10..29 ascending
        float cls = 0.f, d;
        d = b5.x - a5.x;   cls += d * d;  d = b5.y - a5.y;   cls += d * d;
        d = b6.x - a6.x;   cls += d * d;  d = b6.y - a6.y;   cls += d * d;
        d = b7.x - a7.x;   cls += d * d;  d = b7.y - a7.y;   cls += d * d;
        d = b8.x - a8.x;   cls += d * d;  d = b8.y - a8.y;   cls += d * d;
        d = b9.x - a9.x;   cls += d * d;  d = b9.y - a9.y;   cls += d * d;
        d = b10.x - a10.x; cls += d * d;  d = b10.y - a10.y; cls += d * d;
        d = b11.x - a11.x; cls += d * d;  d = b11.y - a11.y; cls += d * d;
        d = b12.x - a12.x; cls += d * d;  d = b12.y - a12.y; cls += d * d;
        d = b13.x - a13.x; cls += d * d;  d = b13.y - a13.y; cls += d * d;
        d = b14.x - a14.x; cls += d * d;  d = b14.y - a14.y; cls += d * d;
        s4 += m * cls;
    }

    // ---- single-wave butterfly reduce ----
#pragma unroll
    for (int o = 32; o > 0; o >>= 1) {
        s0 += __shfl_down(s0, o);
        s1 += __shfl_down(s1, o);
        s2 += __shfl_down(s2, o);
        s3 += __shfl_down(s3, o);
        s4 += __shfl_down(s4, o);
    }
    if (lane == 0) {
        partA[blockIdx.x] = make_float4(s0, s1, s2, s3);
        partB[blockIdx.x] = s4;
    }

    // ---- completion counter: last block reduces all partials ----
    __threadfence();                       // device-scope: partials visible
    u32 old = 0;
    if (lane == 0) old = atomicAdd(counter, 1u);
    old = __shfl(old, 0);
    if (old == (u32)nblocks - 1u) {
        __threadfence();                   // acquire side
        asm volatile("" ::: "memory");     // no load hoisting above the fence
        float r0 = 0.f, r1 = 0.f, r2 = 0.f, r3 = 0.f, r4 = 0.f;
        for (int i = lane; i < nblocks; i += 64) {
            float4 v = partA[i];
            r0 += v.x; r1 += v.y; r2 += v.z; r3 += v.w;
            r4 += partB[i];
        }
#pragma unroll
        for (int o = 32; o > 0; o >>= 1) {
            r0 += __shfl_down(r0, o);
            r1 += __shfl_down(r1, o);
            r2 += __shfl_down(r2, o);
            r3 += __shfl_down(r3, o);
            r4 += __shfl_down(r4, o);
        }
        if (lane == 0) {
            float xy     = r0 * 5.0f * invN;
            float wh     = r1 * 5.0f * invN;
            float cobj   = r2 * invN;
            float cnoobj = r3 * 0.5f * invN;
            float cls    = r4 * invN;
            out[0] = xy + wh + cobj + cnoobj + cls;
            out[1] = xy;
            out[2] = wh;
            out[3] = cobj;
            out[4] = cnoobj;
            out[5] = cls;
        }
    }
}

extern "C" void kernel_launch(void* const* d_in, const int* in_sizes, int n_in,
                              void* d_out, int out_size, void* d_ws, size_t ws_size,
                              hipStream_t stream)
{
    const float* pred = (const float*)d_in[0];
    const float* targ = (const float*)d_in[1];
    int ncells = in_sizes[0] / 30;            // 802816
    int ttiles = ncells / CPT;                // 12544 tiles
    int N      = ncells / (SS * SS);

    // tiles-per-block: 4 -> 3136 blocks (12.25/CU available, 10 resident);
    // grow only if d_ws can't hold partials + counter
    int ntiles = 4;
    while ((size_t)(ttiles / ntiles) * 20 + 4 > ws_size && ntiles < 256) ntiles *= 2;
    int blocks = ttiles / ntiles;

    float4* partA = (float4*)d_ws;
    float*  partB = (float*)((char*)d_ws + (size_t)blocks * sizeof(float4));
    u32*    counter = (u32*)((char*)d_ws + (size_t)blocks * 20);

    hipMemsetAsync(counter, 0, sizeof(u32), stream);

    yolo_fused<<<blocks, TPB, 0, stream>>>(pred, targ, partA, partB, counter,
                                           (float*)d_out, ntiles, blocks,
                                           1.0f / (float)N);
}

// Round 14
// 39.324 us; speedup vs baseline: 5.8699x; 5.8699x over previous
//
#include <hip/hip_runtime.h>

// YOLOv1 loss — REVERT to verified best (round 9, 39.2us).
// R13's fused last-block reduce regressed 6x (per-block device-scope
// __threadfence serializes at L2). The 2-kernel structure stands.
// Structure: global_load_lds DMA stages each 128-cell tile raw/linear
// (zero scatter VALU, zero VGPR round-trip); one lane per cell-PAIR
// (240B = 15 float4) with compile-time chunk roles; 1 wave/block ->
// no barriers; per-block partials -> small final reduce kernel.

constexpr int SS  = 14;
constexpr int TPB = 64;                  // one wave
constexpr int CPT = 128;                 // cells per tile (= 64 pairs)
constexpr int TFL = CPT * 30;            // floats per tensor per tile = 3840
constexpr int NLD = TFL / 256;           // 15 x 1KB global_load_lds per tensor

typedef unsigned int u32;
typedef __attribute__((address_space(3))) u32 lds_u32;
typedef __attribute__((address_space(1))) const u32 glb_u32;

__device__ __forceinline__ void box_loss(
    float p0, float p1, float p2, float p3, float p4,
    float p5, float p6, float p7, float p8, float p9,
    float t0, float t1, float t2, float t3, float t4,
    float offx, float offy,
    float& s0, float& s1, float& s2, float& s3, float& m_out)
{
    float m  = (t4 == 1.0f) ? 1.0f : 0.0f;
    float nm = (t4 == 0.0f) ? 1.0f : 0.0f;
    m_out = m;

    const float S = 14.0f;
    float tcx = t0 / S + offx / S;
    float tcy = t1 / S + offy / S;
    float thw = 0.5f * t2, thh = 0.5f * t3;
    float tx0 = tcx - thw, ty0 = tcy - thh;
    float tx1 = tcx + thw, ty1 = tcy + thh;
    float area_t = t2 * t3;

    float iou0, iou1;
    {
        float cx = p0 / S + offx / S, cy = p1 / S + offy / S;
        float hw = 0.5f * p2, hh = 0.5f * p3;
        float x0 = cx - hw, y0 = cy - hh, x1 = cx + hw, y1 = cy + hh;
        float wx = fmaxf(fminf(tx1, x1) - fmaxf(tx0, x0), 0.f);
        float wy = fmaxf(fminf(ty1, y1) - fmaxf(ty0, y0), 0.f);
        float inter = wx * wy;
        iou0 = inter / (area_t + p2 * p3 - inter);
    }
    {
        float cx = p5 / S + offx / S, cy = p6 / S + offy / S;
        float hw = 0.5f * p7, hh = 0.5f * p8;
        float x0 = cx - hw, y0 = cy - hh, x1 = cx + hw, y1 = cy + hh;
        float wx = fmaxf(fminf(tx1, x1) - fmaxf(tx0, x0), 0.f);
        float wy = fmaxf(fminf(ty1, y1) - fmaxf(ty0, y0), 0.f);
        float inter = wx * wy;
        iou1 = inter / (area_t + p7 * p8 - inter);
    }

    int k = (iou1 > iou0) ? 1 : 0;     // jnp.argmax first-max tie-break
    float b0 = k ? p5 : p0, b1 = k ? p6 : p1;
    float b2 = k ? p7 : p2, b3 = k ? p8 : p3, b4 = k ? p9 : p4;
    float biou = k ? iou1 : iou0;

    float d0 = t0 - b0, d1 = t1 - b1;
    s0 += m * (d0 * d0 + d1 * d1);

    float e0 = sqrtf(t2) - sqrtf(b2);
    float e1 = sqrtf(t3) - sqrtf(b3);
    s1 += m * (e0 * e0 + e1 * e1);

    float dc = biou - b4;
    s2 += m * dc * dc;

    float conf_other = k ? p4 : p9;
    s3 += nm * (p4 * p4 + p9 * p9) + m * conf_other * conf_other;
}

__global__ __launch_bounds__(TPB) void yolo_fused(
    const float* __restrict__ pred,
    const float* __restrict__ targ,
    float4* __restrict__ partA,   // per-block {xy, wh, Cobj, Cnoobj}
    float*  __restrict__ partB,   // per-block cls
    int ntiles)
{
    __shared__ __align__(16) float Lraw[2 * TFL];   // [0,TFL): pred, [TFL,2TFL): targ
    const int lane = threadIdx.x;

    float s0 = 0.f, s1 = 0.f, s2 = 0.f, s3 = 0.f, s4 = 0.f;

#pragma unroll 1
    for (int tile = 0; tile < ntiles; ++tile) {
        const size_t tb = (size_t)blockIdx.x * ntiles + tile;
        const float* ps = pred + tb * TFL;
        const float* ts = targ + tb * TFL;

        // previous tile's ds_reads must drain before DMA overwrites LDS
        if (tile) asm volatile("s_waitcnt lgkmcnt(0)" ::: "memory");

        // ---- phase A: raw DMA stage, no VGPR round-trip, no scatter ----
#pragma unroll
        for (int i = 0; i < NLD; ++i)
            __builtin_amdgcn_global_load_lds((glb_u32*)(ps + i * 256 + lane * 4),
                                             (lds_u32*)&Lraw[i * 256], 16, 0, 0);
#pragma unroll
        for (int i = 0; i < NLD; ++i)
            __builtin_amdgcn_global_load_lds((glb_u32*)(ts + i * 256 + lane * 4),
                                             (lds_u32*)&Lraw[TFL + i * 256], 16, 0, 0);
        asm volatile("s_waitcnt vmcnt(0)" ::: "memory");
        __builtin_amdgcn_sched_barrier(0);
        // single wave per block: lanes see their own wave's LDS, no s_barrier

        // ---- phase B: one PAIR per lane, compile-time chunk roles ----
        const float4* Pf = reinterpret_cast<const float4*>(Lraw) + lane * 15;
        const float4* Tf = reinterpret_cast<const float4*>(Lraw + TFL) + lane * 15;
        float4 P0=Pf[0],P1=Pf[1],P2=Pf[2],P3=Pf[3],P4=Pf[4],P5=Pf[5],P6=Pf[6],
               P7=Pf[7],P8=Pf[8],P9=Pf[9],P10=Pf[10],P11=Pf[11],P12=Pf[12],
               P13=Pf[13],P14=Pf[14];
        float4 T0=Tf[0],T1=Tf[1],T2=Tf[2],T3=Tf[3],T4=Tf[4],T5=Tf[5],T6=Tf[6],
               T7=Tf[7],T8=Tf[8],T10=Tf[10],T11=Tf[11],T12=Tf[12],T13=Tf[13],
               T14=Tf[14];                      // T9 (pair elems 36..39) unused

        unsigned gcell0 = (unsigned)tb * CPT + 2u * (unsigned)lane;  // even
        unsigned ij = gcell0 % 196u;
        float offx = (float)(ij % 14u);   // off = (j, i): x = column
        float offy = (float)(ij / 14u);   // even cell -> pair never wraps a row

        float m0, m1;
        // cell0: pred elems 0..9 = P0,P1,P2.xy ; targ 0..4 = T0,T1.x
        box_loss(P0.x,P0.y,P0.z,P0.w,P1.x,P1.y,P1.z,P1.w,P2.x,P2.y,
                 T0.x,T0.y,T0.z,T0.w,T1.x, offx, offy, s0,s1,s2,s3, m0);
        // cell1: pred elems 30..39 = P7.zw,P8,P9 ; targ 30..34 = T7.zw,T8.xyz
        box_loss(P7.z,P7.w,P8.x,P8.y,P8.z,P8.w,P9.x,P9.y,P9.z,P9.w,
                 T7.z,T7.w,T8.x,T8.y,T8.z, offx + 1.0f, offy, s0,s1,s2,s3, m1);

        // class: cell0 elems 10..29 ; cell1 elems 40..59 (ascending order)
        float c0 = 0.f, c1 = 0.f, d;
        d=T2.z-P2.z; c0+=d*d;  d=T2.w-P2.w; c0+=d*d;
        d=T3.x-P3.x; c0+=d*d;  d=T3.y-P3.y; c0+=d*d;
        d=T3.z-P3.z; c0+=d*d;  d=T3.w-P3.w; c0+=d*d;
        d=T4.x-P4.x; c0+=d*d;  d=T4.y-P4.y; c0+=d*d;
        d=T4.z-P4.z; c0+=d*d;  d=T4.w-P4.w; c0+=d*d;
        d=T5.x-P5.x; c0+=d*d;  d=T5.y-P5.y; c0+=d*d;
        d=T5.z-P5.z; c0+=d*d;  d=T5.w-P5.w; c0+=d*d;
        d=T6.x-P6.x; c0+=d*d;  d=T6.y-P6.y; c0+=d*d;
        d=T6.z-P6.z; c0+=d*d;  d=T6.w-P6.w; c0+=d*d;
        d=T7.x-P7.x; c0+=d*d;  d=T7.y-P7.y; c0+=d*d;

        d=T10.x-P10.x; c1+=d*d;  d=T10.y-P10.y; c1+=d*d;
        d=T10.z-P10.z; c1+=d*d;  d=T10.w-P10.w; c1+=d*d;
        d=T11.x-P11.x; c1+=d*d;  d=T11.y-P11.y; c1+=d*d;
        d=T11.z-P11.z; c1+=d*d;  d=T11.w-P11.w; c1+=d*d;
        d=T12.x-P12.x; c1+=d*d;  d=T12.y-P12.y; c1+=d*d;
        d=T12.z-P12.z; c1+=d*d;  d=T12.w-P12.w; c1+=d*d;
        d=T13.x-P13.x; c1+=d*d;  d=T13.y-P13.y; c1+=d*d;
        d=T13.z-P13.z; c1+=d*d;  d=T13.w-P13.w; c1+=d*d;
        d=T14.x-P14.x; c1+=d*d;  d=T14.y-P14.y; c1+=d*d;
        d=T14.z-P14.z; c1+=d*d;  d=T14.w-P14.w; c1+=d*d;

        s4 += m0 * c0 + m1 * c1;
    }

    // ---- single-wave butterfly reduce, no LDS / no barrier ----
#pragma unroll
    for (int o = 32; o > 0; o >>= 1) {
        s0 += __shfl_down(s0, o);
        s1 += __shfl_down(s1, o);
        s2 += __shfl_down(s2, o);
        s3 += __shfl_down(s3, o);
        s4 += __shfl_down(s4, o);
    }
    if (lane == 0) {
        partA[blockIdx.x] = make_float4(s0, s1, s2, s3);
        partB[blockIdx.x] = s4;
    }
}

__global__ __launch_bounds__(1024) void yolo_final(
    const float4* __restrict__ partA, int nA,
    const float* __restrict__ partB,
    float* __restrict__ out, float invN)
{
    float a0 = 0.f, a1 = 0.f, a2 = 0.f, a3 = 0.f, b = 0.f;
    for (int i = threadIdx.x; i < nA; i += 1024) {
        float4 v = partA[i];
        a0 += v.x; a1 += v.y; a2 += v.z; a3 += v.w;
        b += partB[i];
    }
#pragma unroll
    for (int o = 32; o > 0; o >>= 1) {
        a0 += __shfl_down(a0, o);
        a1 += __shfl_down(a1, o);
        a2 += __shfl_down(a2, o);
        a3 += __shfl_down(a3, o);
        b  += __shfl_down(b, o);
    }
    __shared__ float red[16][5];
    int wave = threadIdx.x >> 6;
    if ((threadIdx.x & 63) == 0) {
        red[wave][0] = a0; red[wave][1] = a1; red[wave][2] = a2;
        red[wave][3] = a3; red[wave][4] = b;
    }
    __syncthreads();
    if (threadIdx.x == 0) {
        float r0=0, r1=0, r2=0, r3=0, r4=0;
#pragma unroll
        for (int w = 0; w < 16; ++w) {
            r0 += red[w][0]; r1 += red[w][1]; r2 += red[w][2];
            r3 += red[w][3]; r4 += red[w][4];
        }
        float xy     = r0 * 5.0f * invN;
        float wh     = r1 * 5.0f * invN;
        float cobj   = r2 * invN;
        float cnoobj = r3 * 0.5f * invN;
        float cls    = r4 * invN;
        out[0] = xy + wh + cobj + cnoobj + cls;
        out[1] = xy;
        out[2] = wh;
        out[3] = cobj;
        out[4] = cnoobj;
        out[5] = cls;
    }
}

extern "C" void kernel_launch(void* const* d_in, const int* in_sizes, int n_in,
                              void* d_out, int out_size, void* d_ws, size_t ws_size,
                              hipStream_t stream)
{
    const float* pred = (const float*)d_in[0];
    const float* targ = (const float*)d_in[1];
    int ncells = in_sizes[0] / 30;            // 802816
    int ttiles = ncells / CPT;                // 6272 tiles
    int N      = ncells / (SS * SS);

    // tiles-per-block so per-block partials (20B) fit in d_ws
    int ntiles = 1;
    while ((size_t)(ttiles / ntiles) * 20 + 16 > ws_size && ntiles < 64) ntiles *= 2;
    int blocks = ttiles / ntiles;

    float4* partA = (float4*)d_ws;
    float*  partB = (float*)((char*)d_ws + (size_t)blocks * sizeof(float4));

    yolo_fused<<<blocks, TPB, 0, stream>>>(pred, targ, partA, partB, ntiles);
    yolo_final<<<1, 1024, 0, stream>>>(partA, blocks, partB,
                                       (float*)d_out, 1.0f / (float)N);
}